// Round 5
// baseline (923.058 us; speedup 1.0000x reference)
//
#include <hip/hip_runtime.h>

typedef unsigned short u16;
typedef unsigned int u32;
typedef __attribute__((ext_vector_type(8))) short short8;
typedef __attribute__((ext_vector_type(4))) float f32x4;

constexpr int S_ = 256, I_ = 256, C_ = 256, H_ = 8, D_ = 32, HD_ = 256;
constexpr float MAGIC_L = 1234.0f, MAGIC_Q = 2345.0f, MAGIC_A = 3456.0f;

__device__ __forceinline__ float b2f(u32 u) {
  union { u32 i; float f; } x; x.i = u << 16; return x.f;
}
__device__ __forceinline__ u16 f2b(float f) {
  union { float f; u32 i; } x; x.f = f;
  u32 r = x.i + 0x7fffu + ((x.i >> 16) & 1u);
  return (u16)(r >> 16);
}
__device__ __forceinline__ uint4 pack8(const float* f) {
  uint4 r;
  r.x = (u32)f2b(f[0]) | ((u32)f2b(f[1]) << 16);
  r.y = (u32)f2b(f[2]) | ((u32)f2b(f[3]) << 16);
  r.z = (u32)f2b(f[4]) | ((u32)f2b(f[5]) << 16);
  r.w = (u32)f2b(f[6]) | ((u32)f2b(f[7]) << 16);
  return r;
}
__device__ __forceinline__ void unpack8(const u16* p, float* f) {
  uint4 r = *reinterpret_cast<const uint4*>(p);
  f[0] = b2f(r.x & 0xffffu); f[1] = b2f(r.x >> 16);
  f[2] = b2f(r.y & 0xffffu); f[3] = b2f(r.y >> 16);
  f[4] = b2f(r.z & 0xffffu); f[5] = b2f(r.z >> 16);
  f[6] = b2f(r.w & 0xffffu); f[7] = b2f(r.w >> 16);
}
__device__ __forceinline__ void load8f(const float* p, float* f) {
  float4 a = *reinterpret_cast<const float4*>(p);
  float4 b = *reinterpret_cast<const float4*>(p + 4);
  f[0] = a.x; f[1] = a.y; f[2] = a.z; f[3] = a.w;
  f[4] = b.x; f[5] = b.y; f[6] = b.z; f[7] = b.w;
}
__device__ __forceinline__ f32x4 mfma16(short8 a, short8 b, f32x4 c) {
  return __builtin_amdgcn_mfma_f32_16x16x32_bf16(a, b, c, 0, 0, 0);
}

// ---------------- K0: LayerNorm stats ----------------
__global__ void k_lnstats(const float* __restrict__ m, float* __restrict__ mu,
                          float* __restrict__ rstd, float* __restrict__ flags) {
  if (blockIdx.x == 0 && threadIdx.x == 0) flags[0] = MAGIC_L;
  int wg = (blockIdx.x * blockDim.x + threadIdx.x) >> 6;
  int lane = threadIdx.x & 63;
  for (int it = 0; it < 16; ++it) {
    int row = wg * 16 + it;
    float4 v = *reinterpret_cast<const float4*>(m + (size_t)row * C_ + lane * 4);
    float s = v.x + v.y + v.z + v.w;
    float ss = v.x * v.x + v.y * v.y + v.z * v.z + v.w * v.w;
#pragma unroll
    for (int o = 32; o; o >>= 1) { s += __shfl_xor(s, o); ss += __shfl_xor(ss, o); }
    if (lane == 0) {
      float mn = s * (1.f / C_);
      float var = ss * (1.f / C_) - mn * mn;
      mu[row] = mn;
      rstd[row] = rsqrtf(fmaxf(var, 0.f) + 1e-5f);
    }
  }
}

// ---------------- K1: fused LN + QKVG projection (MFMA, 16KB LDS) ----------------
// grid 16384 = (i[256] x stile[4])<<4 | (mat[4] x colblock[4])
__global__ void k_qkvg(const float* __restrict__ m, const float* __restrict__ mask,
                       const float* __restrict__ lnw, const float* __restrict__ lnb,
                       const float* __restrict__ wq, const float* __restrict__ wk,
                       const float* __restrict__ wv, const float* __restrict__ wg,
                       const float* __restrict__ bg, const float* __restrict__ mu,
                       const float* __restrict__ rstd, u16* __restrict__ qws,
                       u16* __restrict__ kws, u16* __restrict__ vws,
                       u16* __restrict__ gws, float* __restrict__ flags) {
  __shared__ u16 lA[64 * 64];
  __shared__ u16 lB[64 * 64];
  if (blockIdx.x == 0 && threadIdx.x == 0) flags[1] = MAGIC_Q;
  int bid = blockIdx.x;
  int chunkID = bid & 15;
  int tile = bid >> 4;
  int i_col = tile >> 2;
  int s0 = (tile & 3) * 64;
  int mat = chunkID >> 2;
  int cb = (chunkID & 3) * 64;
  const float* W = (mat == 0) ? wq : (mat == 1) ? wk : (mat == 2) ? wv : wg;
  int t = threadIdx.x;
  int lane = t & 63, w = t >> 6;
  int wr = (w >> 1) * 32, wc = (w & 1) * 32;
  int lr = lane & 15, lk = lane >> 4;
  f32x4 zz = {0.f, 0.f, 0.f, 0.f};
  f32x4 acc[2][2] = {{zz, zz}, {zz, zz}};
  for (int kc = 0; kc < 4; ++kc) {
    if (kc) __syncthreads();
#pragma unroll
    for (int rep = 0; rep < 2; ++rep) {
      int slot = rep * 256 + t;
      int row = slot >> 3, seg = slot & 7;
      int k0 = kc * 64 + seg * 8;
      int s = s0 + row;
      int rg = s * I_ + i_col;
      float xf[8], wv8[8], bv8[8], yf[8], wf[8];
      load8f(m + (size_t)rg * C_ + k0, xf);
      load8f(lnw + k0, wv8);
      load8f(lnb + k0, bv8);
      float mean = mu[rg], rs = rstd[rg], mkv = mask[rg];
#pragma unroll
      for (int u = 0; u < 8; ++u) yf[u] = ((xf[u] - mean) * rs * wv8[u] + bv8[u]) * mkv;
      *reinterpret_cast<uint4*>(&lA[row * 64 + ((seg * 8) ^ ((row & 7) << 3))]) = pack8(yf);
      load8f(W + (size_t)(cb + row) * C_ + k0, wf);
      *reinterpret_cast<uint4*>(&lB[row * 64 + ((seg * 8) ^ ((row & 7) << 3))]) = pack8(wf);
    }
    __syncthreads();
#pragma unroll
    for (int kk = 0; kk < 2; ++kk) {
      int kb = kk * 32 + lk * 8;
      int ra0 = wr + lr, ra1 = wr + 16 + lr, rb0 = wc + lr, rb1 = wc + 16 + lr;
      short8 a0 = *reinterpret_cast<const short8*>(&lA[ra0 * 64 + (kb ^ ((ra0 & 7) << 3))]);
      short8 a1 = *reinterpret_cast<const short8*>(&lA[ra1 * 64 + (kb ^ ((ra1 & 7) << 3))]);
      short8 b0 = *reinterpret_cast<const short8*>(&lB[rb0 * 64 + (kb ^ ((rb0 & 7) << 3))]);
      short8 b1 = *reinterpret_cast<const short8*>(&lB[rb1 * 64 + (kb ^ ((rb1 & 7) << 3))]);
      acc[0][0] = mfma16(a0, b0, acc[0][0]);
      acc[0][1] = mfma16(a0, b1, acc[0][1]);
      acc[1][0] = mfma16(a1, b0, acc[1][0]);
      acc[1][1] = mfma16(a1, b1, acc[1][1]);
    }
  }
  u16* dstp = (mat == 0) ? qws : (mat == 1) ? kws : (mat == 2) ? vws : gws;
#pragma unroll
  for (int mm = 0; mm < 2; ++mm) {
#pragma unroll
    for (int nn = 0; nn < 2; ++nn) {
      int colL = wc + nn * 16 + lr;
      int hd = cb + colL;
      int h = hd >> 5, d = hd & 31;
      float bgv = (mat == 3) ? bg[hd] : 0.f;
#pragma unroll
      for (int r = 0; r < 4; ++r) {
        int rowL = wr + mm * 16 + lk * 4 + r;
        int s = s0 + rowL;
        float v = acc[mm][nn][r];
        size_t dst = (((size_t)i_col * H_ + h) * S_ + s) * D_ + d;
        if (mat == 3) {
          float mkv = mask[s * I_ + i_col];
          v = mkv * (1.f / (1.f + __expf(-(v + bgv))));
        }
        dstp[dst] = f2b(v);
      }
    }
  }
}

// ---------------- K2: attention per (i,h), 256 threads, 1 row/thread ----------------
__global__ void k_attn(u16* __restrict__ qws, const u16* __restrict__ kws,
                       const u16* __restrict__ vws, const u16* __restrict__ gws,
                       const float* __restrict__ mask, float* __restrict__ flags) {
  __shared__ u16 lK[256 * 32];
  __shared__ u16 lV[256 * 32];
  __shared__ float lMk[256];
  if (blockIdx.x == 0 && threadIdx.x == 0) flags[2] = MAGIC_A;
  int bid = blockIdx.x;
  int i = bid >> 3, h = bid & 7;
  int t = threadIdx.x;
  size_t base = ((size_t)i * H_ + h) * (size_t)(S_ * D_);
#pragma unroll
  for (int c = 0; c < 4; ++c) {
    *reinterpret_cast<uint4*>(&lK[t * 32 + c * 8]) =
        *reinterpret_cast<const uint4*>(kws + base + t * 32 + c * 8);
    *reinterpret_cast<uint4*>(&lV[t * 32 + c * 8]) =
        *reinterpret_cast<const uint4*>(vws + base + t * 32 + c * 8);
  }
  lMk[t] = mask[t * I_ + i];
  __syncthreads();
  const float qscale = 0.17677669529663687f;  // 1/sqrt(32)
  float qa[32];
  {
    const u16* Q = qws + base + (size_t)t * D_;
#pragma unroll
    for (int c = 0; c < 4; ++c) {
      float f[8];
      unpack8(Q + c * 8, f);
#pragma unroll
      for (int u = 0; u < 8; ++u) qa[c * 8 + u] = f[u] * qscale;
    }
  }
  float mA = -1e30f, sumA = 0.f;
  float oA[32] = {0.f};
  for (int t0 = 0; t0 < 256; t0 += 16) {
    float pA[16];
#pragma unroll
    for (int j = 0; j < 16; ++j) {
      const u16* kr = &lK[(t0 + j) * 32];
      float a0 = 0.f;
#pragma unroll
      for (int c = 0; c < 4; ++c) {
        float kf[8];
        unpack8(kr + c * 8, kf);
#pragma unroll
        for (int u = 0; u < 8; ++u) a0 = fmaf(qa[c * 8 + u], kf[u], a0);
      }
      pA[j] = lMk[t0 + j] > 0.f ? a0 : -1e9f;
    }
    float tma = pA[0];
#pragma unroll
    for (int j = 1; j < 16; ++j) tma = fmaxf(tma, pA[j]);
    float nA = fmaxf(mA, tma);
    float cA = __expf(mA - nA);
    mA = nA;
    sumA *= cA;
#pragma unroll
    for (int d = 0; d < 32; ++d) oA[d] *= cA;
#pragma unroll
    for (int j = 0; j < 16; ++j) { pA[j] = __expf(pA[j] - mA); sumA += pA[j]; }
#pragma unroll
    for (int j = 0; j < 16; ++j) {
      const u16* vr = &lV[(t0 + j) * 32];
      float pa = pA[j];
#pragma unroll
      for (int c = 0; c < 4; ++c) {
        float vf[8];
        unpack8(vr + c * 8, vf);
#pragma unroll
        for (int u = 0; u < 8; ++u) oA[c * 8 + u] = fmaf(pa, vf[u], oA[c * 8 + u]);
      }
    }
  }
  float ivA = 1.f / sumA;
  // O row t is thread-exclusive: overwrite q in place (q already consumed).
  const u16* G = gws + base + (size_t)t * D_;
  u16* O = qws + base + (size_t)t * D_;
#pragma unroll
  for (int c = 0; c < 4; ++c) {
    float gf[8], vv[8];
    unpack8(G + c * 8, gf);
#pragma unroll
    for (int u = 0; u < 8; ++u) vv[u] = oA[c * 8 + u] * ivA * gf[u];
    *reinterpret_cast<uint4*>(O + c * 8) = pack8(vv);
  }
}

// ---------------- K3: output projection (MFMA) + bias + transpose, f32 out ----------------
__global__ void k_oproj(const u16* __restrict__ ows, const float* __restrict__ wo,
                        const float* __restrict__ bo, const float* __restrict__ flags,
                        float* __restrict__ out) {
  __shared__ u16 lA[64 * 64];
  __shared__ u16 lB[64 * 64];
  float fb = 0.f;
  {
    float f0 = flags[0], f1 = flags[1], f2 = flags[2];
    fb = (f0 != MAGIC_L) ? 200.0f : (f1 != MAGIC_Q) ? 300.0f : (f2 != MAGIC_A) ? 400.0f : 0.0f;
  }
  int bid = blockIdx.x;
  int chunkID = bid & 3;
  int tile = bid >> 2;
  int r0 = tile * 64;
  int cb = chunkID * 64;
  int t = threadIdx.x;
  int lane = t & 63, w = t >> 6;
  int wr = (w >> 1) * 32, wc = (w & 1) * 32;
  int lr = lane & 15, lk = lane >> 4;
  f32x4 zz = {0.f, 0.f, 0.f, 0.f};
  f32x4 acc[2][2] = {{zz, zz}, {zz, zz}};
  for (int kc = 0; kc < 4; ++kc) {
    if (kc) __syncthreads();
#pragma unroll
    for (int rep = 0; rep < 2; ++rep) {
      int slot = rep * 256 + t;
      int row = slot >> 3, seg = slot & 7;
      int rg = r0 + row;
      int ii = rg >> 8, ss = rg & 255;
      int k0 = kc * 64 + seg * 8;
      int hh = k0 >> 5, dd = k0 & 31;
      *reinterpret_cast<uint4*>(&lA[row * 64 + ((seg * 8) ^ ((row & 7) << 3))]) =
          *reinterpret_cast<const uint4*>(ows + (((size_t)ii * H_ + hh) * S_ + ss) * D_ + dd);
      float wf[8];
      load8f(wo + (size_t)(cb + row) * HD_ + k0, wf);
      *reinterpret_cast<uint4*>(&lB[row * 64 + ((seg * 8) ^ ((row & 7) << 3))]) = pack8(wf);
    }
    __syncthreads();
#pragma unroll
    for (int kk = 0; kk < 2; ++kk) {
      int kb = kk * 32 + lk * 8;
      int ra0 = wr + lr, ra1 = wr + 16 + lr, rb0 = wc + lr, rb1 = wc + 16 + lr;
      short8 a0 = *reinterpret_cast<const short8*>(&lA[ra0 * 64 + (kb ^ ((ra0 & 7) << 3))]);
      short8 a1 = *reinterpret_cast<const short8*>(&lA[ra1 * 64 + (kb ^ ((ra1 & 7) << 3))]);
      short8 b0 = *reinterpret_cast<const short8*>(&lB[rb0 * 64 + (kb ^ ((rb0 & 7) << 3))]);
      short8 b1 = *reinterpret_cast<const short8*>(&lB[rb1 * 64 + (kb ^ ((rb1 & 7) << 3))]);
      acc[0][0] = mfma16(a0, b0, acc[0][0]);
      acc[0][1] = mfma16(a0, b1, acc[0][1]);
      acc[1][0] = mfma16(a1, b0, acc[1][0]);
      acc[1][1] = mfma16(a1, b1, acc[1][1]);
    }
  }
#pragma unroll
  for (int mm = 0; mm < 2; ++mm) {
#pragma unroll
    for (int nn = 0; nn < 2; ++nn) {
      int colL = wc + nn * 16 + lr;
      int ch = cb + colL;
      float bov = bo[ch];
#pragma unroll
      for (int r = 0; r < 4; ++r) {
        int rowL = wr + mm * 16 + lk * 4 + r;
        int rg = r0 + rowL;
        int ii = rg >> 8;
        int ss = rg & 255;
        float v = acc[mm][nn][r] + bov;
        if (fb != 0.f) v = fb;
        out[((size_t)ss * I_ + ii) * C_ + ch] = v;
      }
    }
  }
}

extern "C" void kernel_launch(void* const* d_in, const int* in_sizes, int n_in,
                              void* d_out, int out_size, void* d_ws, size_t ws_size,
                              hipStream_t stream) {
  const float *m, *mask, *lnw, *lnb, *wq, *wk, *wv, *wg, *bg, *wo, *bo;
  if (in_sizes[0] > 1000000) {  // dict order
    m = (const float*)d_in[0]; mask = (const float*)d_in[1];
    lnw = (const float*)d_in[2]; lnb = (const float*)d_in[3];
    wq = (const float*)d_in[4]; wk = (const float*)d_in[5];
    wv = (const float*)d_in[6]; wg = (const float*)d_in[7];
    bg = (const float*)d_in[8]; wo = (const float*)d_in[9];
    bo = (const float*)d_in[10];
  } else {  // alphabetical: bg, bo, ln_b, ln_w, m, msa_mask, wg, wk, wo, wq, wv
    bg = (const float*)d_in[0]; bo = (const float*)d_in[1];
    lnb = (const float*)d_in[2]; lnw = (const float*)d_in[3];
    m = (const float*)d_in[4]; mask = (const float*)d_in[5];
    wg = (const float*)d_in[6]; wk = (const float*)d_in[7];
    wo = (const float*)d_in[8]; wq = (const float*)d_in[9];
    wv = (const float*)d_in[10];
  }
  float* out = (float*)d_out;

  const size_t SZ = (size_t)S_ * I_ * C_;  // 16,777,216
  u16* qws = (u16*)d_ws;   // q, later overwritten with gated attention output O
  u16* kws = qws + SZ;
  u16* vws = kws + SZ;
  u16* gws = vws + SZ;
  float* mu = (float*)(gws + SZ);
  float* rstd = mu + (S_ * I_);
  float* flags = rstd + (S_ * I_);

  k_lnstats<<<1024, 256, 0, stream>>>(m, mu, rstd, flags);
  k_qkvg<<<16384, 256, 0, stream>>>(m, mask, lnw, lnb, wq, wk, wv, wg, bg, mu,
                                    rstd, qws, kws, vws, gws, flags);
  k_attn<<<2048, 256, 0, stream>>>(qws, kws, vws, gws, mask, flags);
  k_oproj<<<4096, 256, 0, stream>>>(qws, wo, bo, flags, out);
}

// Round 6
// 366.692 us; speedup vs baseline: 2.5173x; 2.5173x over previous
//
#include <hip/hip_runtime.h>

typedef unsigned short u16;
typedef unsigned int u32;
typedef __attribute__((ext_vector_type(8))) short short8;
typedef __attribute__((ext_vector_type(4))) float f32x4;

constexpr int S_ = 256, I_ = 256, C_ = 256, H_ = 8, D_ = 32, HD_ = 256;
constexpr float MAGIC_L = 1234.0f, MAGIC_Q = 2345.0f, MAGIC_A = 3456.0f;
constexpr float QSCALE = 0.17677669529663687f;  // 1/sqrt(32)

__device__ __forceinline__ float b2f(u32 u) {
  union { u32 i; float f; } x; x.i = u << 16; return x.f;
}
__device__ __forceinline__ u16 f2b(float f) {
  union { float f; u32 i; } x; x.f = f;
  u32 r = x.i + 0x7fffu + ((x.i >> 16) & 1u);
  return (u16)(r >> 16);
}
__device__ __forceinline__ uint4 pack8(const float* f) {
  uint4 r;
  r.x = (u32)f2b(f[0]) | ((u32)f2b(f[1]) << 16);
  r.y = (u32)f2b(f[2]) | ((u32)f2b(f[3]) << 16);
  r.z = (u32)f2b(f[4]) | ((u32)f2b(f[5]) << 16);
  r.w = (u32)f2b(f[6]) | ((u32)f2b(f[7]) << 16);
  return r;
}
__device__ __forceinline__ void load8f(const float* p, float* f) {
  float4 a = *reinterpret_cast<const float4*>(p);
  float4 b = *reinterpret_cast<const float4*>(p + 4);
  f[0] = a.x; f[1] = a.y; f[2] = a.z; f[3] = a.w;
  f[4] = b.x; f[5] = b.y; f[6] = b.z; f[7] = b.w;
}
__device__ __forceinline__ f32x4 mfma16(short8 a, short8 b, f32x4 c) {
  return __builtin_amdgcn_mfma_f32_16x16x32_bf16(a, b, c, 0, 0, 0);
}

// ---------------- K0: LayerNorm stats ----------------
__global__ void k_lnstats(const float* __restrict__ m, float* __restrict__ mu,
                          float* __restrict__ rstd, float* __restrict__ flags) {
  if (blockIdx.x == 0 && threadIdx.x == 0) flags[0] = MAGIC_L;
  int wg = (blockIdx.x * blockDim.x + threadIdx.x) >> 6;
  int lane = threadIdx.x & 63;
  for (int it = 0; it < 16; ++it) {
    int row = wg * 16 + it;
    float4 v = *reinterpret_cast<const float4*>(m + (size_t)row * C_ + lane * 4);
    float s = v.x + v.y + v.z + v.w;
    float ss = v.x * v.x + v.y * v.y + v.z * v.z + v.w * v.w;
#pragma unroll
    for (int o = 32; o; o >>= 1) { s += __shfl_xor(s, o); ss += __shfl_xor(ss, o); }
    if (lane == 0) {
      float mn = s * (1.f / C_);
      float var = ss * (1.f / C_) - mn * mn;
      mu[row] = mn;
      rstd[row] = rsqrtf(fmaxf(var, 0.f) + 1e-5f);
    }
  }
}

// ---------------- K1: fused LN + QKVG projection (MFMA) ----------------
// q pre-scaled by 1/sqrt(d); v written TRANSPOSED [i][h][d][s]; gate sigmoid'd.
__global__ void k_qkvg(const float* __restrict__ m, const float* __restrict__ mask,
                       const float* __restrict__ lnw, const float* __restrict__ lnb,
                       const float* __restrict__ wq, const float* __restrict__ wk,
                       const float* __restrict__ wv, const float* __restrict__ wg,
                       const float* __restrict__ bg, const float* __restrict__ mu,
                       const float* __restrict__ rstd, u16* __restrict__ qws,
                       u16* __restrict__ kws, u16* __restrict__ vws,
                       u16* __restrict__ gws, float* __restrict__ flags) {
  __shared__ u16 lA[64 * 64];
  __shared__ u16 lB[64 * 64];
  if (blockIdx.x == 0 && threadIdx.x == 0) flags[1] = MAGIC_Q;
  int bid = blockIdx.x;
  int chunkID = bid & 15;
  int tile = bid >> 4;
  int i_col = tile >> 2;
  int s0 = (tile & 3) * 64;
  int mat = chunkID >> 2;
  int cb = (chunkID & 3) * 64;
  const float* W = (mat == 0) ? wq : (mat == 1) ? wk : (mat == 2) ? wv : wg;
  int t = threadIdx.x;
  int lane = t & 63, w = t >> 6;
  int wr = (w >> 1) * 32, wc = (w & 1) * 32;
  int lr = lane & 15, lk = lane >> 4;
  f32x4 zz = {0.f, 0.f, 0.f, 0.f};
  f32x4 acc[2][2] = {{zz, zz}, {zz, zz}};
  for (int kc = 0; kc < 4; ++kc) {
    if (kc) __syncthreads();
#pragma unroll
    for (int rep = 0; rep < 2; ++rep) {
      int slot = rep * 256 + t;
      int row = slot >> 3, seg = slot & 7;
      int k0 = kc * 64 + seg * 8;
      int s = s0 + row;
      int rg = s * I_ + i_col;
      float xf[8], wv8[8], bv8[8], yf[8], wf[8];
      load8f(m + (size_t)rg * C_ + k0, xf);
      load8f(lnw + k0, wv8);
      load8f(lnb + k0, bv8);
      float mean = mu[rg], rs = rstd[rg], mkv = mask[rg];
#pragma unroll
      for (int u = 0; u < 8; ++u) yf[u] = ((xf[u] - mean) * rs * wv8[u] + bv8[u]) * mkv;
      *reinterpret_cast<uint4*>(&lA[row * 64 + ((seg * 8) ^ ((row & 7) << 3))]) = pack8(yf);
      load8f(W + (size_t)(cb + row) * C_ + k0, wf);
      *reinterpret_cast<uint4*>(&lB[row * 64 + ((seg * 8) ^ ((row & 7) << 3))]) = pack8(wf);
    }
    __syncthreads();
#pragma unroll
    for (int kk = 0; kk < 2; ++kk) {
      int kb = kk * 32 + lk * 8;
      int ra0 = wr + lr, ra1 = wr + 16 + lr, rb0 = wc + lr, rb1 = wc + 16 + lr;
      short8 a0 = *reinterpret_cast<const short8*>(&lA[ra0 * 64 + (kb ^ ((ra0 & 7) << 3))]);
      short8 a1 = *reinterpret_cast<const short8*>(&lA[ra1 * 64 + (kb ^ ((ra1 & 7) << 3))]);
      short8 b0 = *reinterpret_cast<const short8*>(&lB[rb0 * 64 + (kb ^ ((rb0 & 7) << 3))]);
      short8 b1 = *reinterpret_cast<const short8*>(&lB[rb1 * 64 + (kb ^ ((rb1 & 7) << 3))]);
      acc[0][0] = mfma16(a0, b0, acc[0][0]);
      acc[0][1] = mfma16(a0, b1, acc[0][1]);
      acc[1][0] = mfma16(a1, b0, acc[1][0]);
      acc[1][1] = mfma16(a1, b1, acc[1][1]);
    }
  }
  u16* dstp = (mat == 0) ? qws : (mat == 1) ? kws : (mat == 2) ? vws : gws;
#pragma unroll
  for (int mm = 0; mm < 2; ++mm) {
#pragma unroll
    for (int nn = 0; nn < 2; ++nn) {
      int colL = wc + nn * 16 + lr;
      int hd = cb + colL;
      int h = hd >> 5, d = hd & 31;
      float bgv = (mat == 3) ? bg[hd] : 0.f;
#pragma unroll
      for (int r = 0; r < 4; ++r) {
        int rowL = wr + mm * 16 + lk * 4 + r;
        int s = s0 + rowL;
        float v = acc[mm][nn][r];
        size_t dst;
        if (mat == 2)
          dst = (((size_t)i_col * H_ + h) * D_ + d) * S_ + s;  // V transposed
        else
          dst = (((size_t)i_col * H_ + h) * S_ + s) * D_ + d;
        if (mat == 0) v *= QSCALE;
        if (mat == 3) {
          float mkv = mask[s * I_ + i_col];
          v = mkv * (1.f / (1.f + __expf(-(v + bgv))));
        }
        dstp[dst] = f2b(v);
      }
    }
  }
}

// ---------------- K2: MFMA flash attention per (i,h) ----------------
// 16 waves x 16 q-rows. S^T = mfma(K,Q) so softmax is lane-local per q-col.
// P^T -> A-frag relayout via 8 ds_bpermute; PV uses V^T LDS rows.
__global__ __launch_bounds__(1024) void k_attn(
    u16* __restrict__ qws, const u16* __restrict__ kws,
    const u16* __restrict__ vws, const u16* __restrict__ gws,
    const float* __restrict__ mask, float* __restrict__ flags) {
  __shared__ u16 lK[256 * 40];   // +16B row pad: conflict-free A-frag reads
  __shared__ u16 lV[32 * 264];   // V^T rows, +16B pad
  __shared__ float lMk[256];
  if (blockIdx.x == 0 && threadIdx.x == 0) flags[2] = MAGIC_A;
  int bid = blockIdx.x;
  int i = bid >> 3, h = bid & 7;
  int t = threadIdx.x;
  size_t base = ((size_t)i * H_ + h) * (size_t)(S_ * D_);
  {
    int s = t >> 2, part = t & 3;
    *reinterpret_cast<uint4*>(&lK[s * 40 + part * 8]) =
        *reinterpret_cast<const uint4*>(kws + base + s * 32 + part * 8);
    int d = t >> 5, p2 = t & 31;
    *reinterpret_cast<uint4*>(&lV[d * 264 + p2 * 8]) =
        *reinterpret_cast<const uint4*>(vws + base + d * 256 + p2 * 8);
    if (t < 256) lMk[t] = mask[t * I_ + i];
  }
  __syncthreads();
  int lane = t & 63;
  int wvid = t >> 6;
  int lq = lane & 15, g = lane >> 4;
  int qbase = wvid * 16;
  short8 qf = *reinterpret_cast<const short8*>(qws + base + (size_t)(qbase + lq) * D_ + g * 8);
  f32x4 zz = {0.f, 0.f, 0.f, 0.f};
  f32x4 o0 = zz, o1 = zz;
  float mcur = -1e30f, sumd = 0.f;
  // bpermute addrs: P relayout src lane = lq + ((g&1)*2 + (w>>1))*16
  int addrP0 = (lq + ((g & 1) * 2 + 0) * 16) * 4;
  int addrP1 = (lq + ((g & 1) * 2 + 1) * 16) * 4;
  // c/iv broadcast to O-layout rows q = g*4+r (src lanes 0..15 hold q=lq)
  int aC0 = (g * 4 + 0) * 4, aC1 = (g * 4 + 1) * 4;
  int aC2 = (g * 4 + 2) * 4, aC3 = (g * 4 + 3) * 4;
#pragma unroll
  for (int ks = 0; ks < 8; ++ks) {
    int k0 = ks * 32;
    short8 kf0 = *reinterpret_cast<const short8*>(&lK[(k0 + lq) * 40 + g * 8]);
    short8 kf1 = *reinterpret_cast<const short8*>(&lK[(k0 + 16 + lq) * 40 + g * 8]);
    f32x4 s0 = mfma16(kf0, qf, zz);
    f32x4 s1 = mfma16(kf1, qf, zz);
    float4 mk0 = *reinterpret_cast<const float4*>(&lMk[k0 + g * 4]);
    float4 mk1 = *reinterpret_cast<const float4*>(&lMk[k0 + 16 + g * 4]);
    float sv[8];
    sv[0] = mk0.x > 0.f ? s0[0] : -1e9f;
    sv[1] = mk0.y > 0.f ? s0[1] : -1e9f;
    sv[2] = mk0.z > 0.f ? s0[2] : -1e9f;
    sv[3] = mk0.w > 0.f ? s0[3] : -1e9f;
    sv[4] = mk1.x > 0.f ? s1[0] : -1e9f;
    sv[5] = mk1.y > 0.f ? s1[1] : -1e9f;
    sv[6] = mk1.z > 0.f ? s1[2] : -1e9f;
    sv[7] = mk1.w > 0.f ? s1[3] : -1e9f;
    float tmax = fmaxf(fmaxf(fmaxf(sv[0], sv[1]), fmaxf(sv[2], sv[3])),
                       fmaxf(fmaxf(sv[4], sv[5]), fmaxf(sv[6], sv[7])));
    tmax = fmaxf(tmax, __shfl_xor(tmax, 16));
    tmax = fmaxf(tmax, __shfl_xor(tmax, 32));
    float mnew = fmaxf(mcur, tmax);
    float c = __expf(mcur - mnew);
    mcur = mnew;
    float p[8];
#pragma unroll
    for (int j = 0; j < 8; ++j) p[j] = __expf(sv[j] - mnew);
    sumd = sumd * c + ((p[0] + p[1]) + (p[2] + p[3])) + ((p[4] + p[5]) + (p[6] + p[7]));
    u32 pk00 = (u32)f2b(p[0]) | ((u32)f2b(p[1]) << 16);
    u32 pk01 = (u32)f2b(p[2]) | ((u32)f2b(p[3]) << 16);
    u32 pk10 = (u32)f2b(p[4]) | ((u32)f2b(p[5]) << 16);
    u32 pk11 = (u32)f2b(p[6]) | ((u32)f2b(p[7]) << 16);
    int b00 = __builtin_amdgcn_ds_bpermute(addrP0, (int)pk00);
    int b10 = __builtin_amdgcn_ds_bpermute(addrP0, (int)pk10);
    int b01 = __builtin_amdgcn_ds_bpermute(addrP0, (int)pk01);
    int b11 = __builtin_amdgcn_ds_bpermute(addrP0, (int)pk11);
    int b02 = __builtin_amdgcn_ds_bpermute(addrP1, (int)pk00);
    int b12 = __builtin_amdgcn_ds_bpermute(addrP1, (int)pk10);
    int b03 = __builtin_amdgcn_ds_bpermute(addrP1, (int)pk01);
    int b13 = __builtin_amdgcn_ds_bpermute(addrP1, (int)pk11);
    union { int u[4]; short8 s8; } pu;
    bool lo = (g < 2);
    pu.u[0] = lo ? b00 : b10;
    pu.u[1] = lo ? b01 : b11;
    pu.u[2] = lo ? b02 : b12;
    pu.u[3] = lo ? b03 : b13;
    float co0 = __int_as_float(__builtin_amdgcn_ds_bpermute(aC0, __float_as_int(c)));
    float co1 = __int_as_float(__builtin_amdgcn_ds_bpermute(aC1, __float_as_int(c)));
    float co2 = __int_as_float(__builtin_amdgcn_ds_bpermute(aC2, __float_as_int(c)));
    float co3 = __int_as_float(__builtin_amdgcn_ds_bpermute(aC3, __float_as_int(c)));
    o0[0] *= co0; o0[1] *= co1; o0[2] *= co2; o0[3] *= co3;
    o1[0] *= co0; o1[1] *= co1; o1[2] *= co2; o1[3] *= co3;
    short8 vf0 = *reinterpret_cast<const short8*>(&lV[lq * 264 + k0 + g * 8]);
    short8 vf1 = *reinterpret_cast<const short8*>(&lV[(16 + lq) * 264 + k0 + g * 8]);
    o0 = mfma16(pu.s8, vf0, o0);
    o1 = mfma16(pu.s8, vf1, o1);
  }
  float s2 = sumd + __shfl_xor(sumd, 16);
  float tot = s2 + __shfl_xor(s2, 32);
  float iv = 1.f / tot;
  float ivo[4];
  ivo[0] = __int_as_float(__builtin_amdgcn_ds_bpermute(aC0, __float_as_int(iv)));
  ivo[1] = __int_as_float(__builtin_amdgcn_ds_bpermute(aC1, __float_as_int(iv)));
  ivo[2] = __int_as_float(__builtin_amdgcn_ds_bpermute(aC2, __float_as_int(iv)));
  ivo[3] = __int_as_float(__builtin_amdgcn_ds_bpermute(aC3, __float_as_int(iv)));
#pragma unroll
  for (int r = 0; r < 4; ++r) {
    int row = qbase + g * 4 + r;
    size_t idx0 = base + (size_t)row * D_ + lq;
    size_t idx1 = idx0 + 16;
    float g0 = b2f((u32)gws[idx0]);
    float g1 = b2f((u32)gws[idx1]);
    qws[idx0] = f2b(o0[r] * ivo[r] * g0);   // O overwrites q buffer (own rows)
    qws[idx1] = f2b(o1[r] * ivo[r] * g1);
  }
}

// ---------------- K3: output projection (MFMA) + bias + transpose, f32 out ----------------
__global__ void k_oproj(const u16* __restrict__ ows, const float* __restrict__ wo,
                        const float* __restrict__ bo, const float* __restrict__ flags,
                        float* __restrict__ out) {
  __shared__ u16 lA[64 * 64];
  __shared__ u16 lB[64 * 64];
  float fb = 0.f;
  {
    float f0 = flags[0], f1 = flags[1], f2 = flags[2];
    fb = (f0 != MAGIC_L) ? 200.0f : (f1 != MAGIC_Q) ? 300.0f : (f2 != MAGIC_A) ? 400.0f : 0.0f;
  }
  int bid = blockIdx.x;
  int chunkID = bid & 3;
  int tile = bid >> 2;
  int r0 = tile * 64;
  int cb = chunkID * 64;
  int t = threadIdx.x;
  int lane = t & 63, w = t >> 6;
  int wr = (w >> 1) * 32, wc = (w & 1) * 32;
  int lr = lane & 15, lk = lane >> 4;
  f32x4 zz = {0.f, 0.f, 0.f, 0.f};
  f32x4 acc[2][2] = {{zz, zz}, {zz, zz}};
  for (int kc = 0; kc < 4; ++kc) {
    if (kc) __syncthreads();
#pragma unroll
    for (int rep = 0; rep < 2; ++rep) {
      int slot = rep * 256 + t;
      int row = slot >> 3, seg = slot & 7;
      int rg = r0 + row;
      int ii = rg >> 8, ss = rg & 255;
      int k0 = kc * 64 + seg * 8;
      int hh = k0 >> 5, dd = k0 & 31;
      *reinterpret_cast<uint4*>(&lA[row * 64 + ((seg * 8) ^ ((row & 7) << 3))]) =
          *reinterpret_cast<const uint4*>(ows + (((size_t)ii * H_ + hh) * S_ + ss) * D_ + dd);
      float wf[8];
      load8f(wo + (size_t)(cb + row) * HD_ + k0, wf);
      *reinterpret_cast<uint4*>(&lB[row * 64 + ((seg * 8) ^ ((row & 7) << 3))]) = pack8(wf);
    }
    __syncthreads();
#pragma unroll
    for (int kk = 0; kk < 2; ++kk) {
      int kb = kk * 32 + lk * 8;
      int ra0 = wr + lr, ra1 = wr + 16 + lr, rb0 = wc + lr, rb1 = wc + 16 + lr;
      short8 a0 = *reinterpret_cast<const short8*>(&lA[ra0 * 64 + (kb ^ ((ra0 & 7) << 3))]);
      short8 a1 = *reinterpret_cast<const short8*>(&lA[ra1 * 64 + (kb ^ ((ra1 & 7) << 3))]);
      short8 b0 = *reinterpret_cast<const short8*>(&lB[rb0 * 64 + (kb ^ ((rb0 & 7) << 3))]);
      short8 b1 = *reinterpret_cast<const short8*>(&lB[rb1 * 64 + (kb ^ ((rb1 & 7) << 3))]);
      acc[0][0] = mfma16(a0, b0, acc[0][0]);
      acc[0][1] = mfma16(a0, b1, acc[0][1]);
      acc[1][0] = mfma16(a1, b0, acc[1][0]);
      acc[1][1] = mfma16(a1, b1, acc[1][1]);
    }
  }
#pragma unroll
  for (int mm = 0; mm < 2; ++mm) {
#pragma unroll
    for (int nn = 0; nn < 2; ++nn) {
      int colL = wc + nn * 16 + lr;
      int ch = cb + colL;
      float bov = bo[ch];
#pragma unroll
      for (int r = 0; r < 4; ++r) {
        int rowL = wr + mm * 16 + lk * 4 + r;
        int rg = r0 + rowL;
        int ii = rg >> 8;
        int ss = rg & 255;
        float v = acc[mm][nn][r] + bov;
        if (fb != 0.f) v = fb;
        out[((size_t)ss * I_ + ii) * C_ + ch] = v;
      }
    }
  }
}

extern "C" void kernel_launch(void* const* d_in, const int* in_sizes, int n_in,
                              void* d_out, int out_size, void* d_ws, size_t ws_size,
                              hipStream_t stream) {
  const float *m, *mask, *lnw, *lnb, *wq, *wk, *wv, *wg, *bg, *wo, *bo;
  if (in_sizes[0] > 1000000) {  // dict order
    m = (const float*)d_in[0]; mask = (const float*)d_in[1];
    lnw = (const float*)d_in[2]; lnb = (const float*)d_in[3];
    wq = (const float*)d_in[4]; wk = (const float*)d_in[5];
    wv = (const float*)d_in[6]; wg = (const float*)d_in[7];
    bg = (const float*)d_in[8]; wo = (const float*)d_in[9];
    bo = (const float*)d_in[10];
  } else {  // alphabetical fallback
    bg = (const float*)d_in[0]; bo = (const float*)d_in[1];
    lnb = (const float*)d_in[2]; lnw = (const float*)d_in[3];
    m = (const float*)d_in[4]; mask = (const float*)d_in[5];
    wg = (const float*)d_in[6]; wk = (const float*)d_in[7];
    wo = (const float*)d_in[8]; wq = (const float*)d_in[9];
    wv = (const float*)d_in[10];
  }
  float* out = (float*)d_out;

  const size_t SZ = (size_t)S_ * I_ * C_;  // 16,777,216
  u16* qws = (u16*)d_ws;   // q (pre-scaled), later overwritten with gated O
  u16* kws = qws + SZ;
  u16* vws = kws + SZ;     // V^T: [i][h][d][s]
  u16* gws = vws + SZ;
  float* mu = (float*)(gws + SZ);
  float* rstd = mu + (S_ * I_);
  float* flags = rstd + (S_ * I_);

  k_lnstats<<<1024, 256, 0, stream>>>(m, mu, rstd, flags);
  k_qkvg<<<16384, 256, 0, stream>>>(m, mask, lnw, lnb, wq, wk, wv, wg, bg, mu,
                                    rstd, qws, kws, vws, gws, flags);
  k_attn<<<2048, 1024, 0, stream>>>(qws, kws, vws, gws, mask, flags);
  k_oproj<<<4096, 256, 0, stream>>>(qws, wo, bo, flags, out);
}

// Round 7
// 246.956 us; speedup vs baseline: 3.7377x; 1.4848x over previous
//
#include <hip/hip_runtime.h>

typedef unsigned short u16;
typedef unsigned int u32;
typedef __attribute__((ext_vector_type(8))) short short8;
typedef __attribute__((ext_vector_type(4))) float f32x4;

constexpr int S_ = 256, I_ = 256, C_ = 256, H_ = 8, D_ = 32, HD_ = 256;
constexpr float QSCALE = 0.17677669529663687f;  // 1/sqrt(32)

__device__ __forceinline__ float b2f(u32 u) {
  union { u32 i; float f; } x; x.i = u << 16; return x.f;
}
__device__ __forceinline__ u16 f2b(float f) {
  union { float f; u32 i; } x; x.f = f;
  u32 r = x.i + 0x7fffu + ((x.i >> 16) & 1u);
  return (u16)(r >> 16);
}
__device__ __forceinline__ uint4 pack8(const float* f) {
  uint4 r;
  r.x = (u32)f2b(f[0]) | ((u32)f2b(f[1]) << 16);
  r.y = (u32)f2b(f[2]) | ((u32)f2b(f[3]) << 16);
  r.z = (u32)f2b(f[4]) | ((u32)f2b(f[5]) << 16);
  r.w = (u32)f2b(f[6]) | ((u32)f2b(f[7]) << 16);
  return r;
}
__device__ __forceinline__ void load8f(const float* p, float* f) {
  float4 a = *reinterpret_cast<const float4*>(p);
  float4 b = *reinterpret_cast<const float4*>(p + 4);
  f[0] = a.x; f[1] = a.y; f[2] = a.z; f[3] = a.w;
  f[4] = b.x; f[5] = b.y; f[6] = b.z; f[7] = b.w;
}
__device__ __forceinline__ f32x4 mfma16(short8 a, short8 b, f32x4 c) {
  return __builtin_amdgcn_mfma_f32_16x16x32_bf16(a, b, c, 0, 0, 0);
}

// ---------------- K0: LayerNorm + mask -> bf16 m_norm ----------------
__global__ void k_lnnorm(const float* __restrict__ m, const float* __restrict__ mask,
                         const float* __restrict__ lnw, const float* __restrict__ lnb,
                         u16* __restrict__ mn) {
  int wg = (blockIdx.x * 256 + threadIdx.x) >> 6;  // 8192 waves
  int lane = threadIdx.x & 63;
  float4 wv = *reinterpret_cast<const float4*>(lnw + lane * 4);
  float4 bv = *reinterpret_cast<const float4*>(lnb + lane * 4);
  for (int it = 0; it < 8; ++it) {
    int row = wg * 8 + it;
    float4 v = *reinterpret_cast<const float4*>(m + (size_t)row * C_ + lane * 4);
    float s = v.x + v.y + v.z + v.w;
    float ss = v.x * v.x + v.y * v.y + v.z * v.z + v.w * v.w;
#pragma unroll
    for (int o = 32; o; o >>= 1) { s += __shfl_xor(s, o); ss += __shfl_xor(ss, o); }
    float mean = s * (1.f / C_);
    float var = ss * (1.f / C_) - mean * mean;
    float rs = rsqrtf(fmaxf(var, 0.f) + 1e-5f);
    float mk = mask[row];
    float y[4];
    y[0] = ((v.x - mean) * rs * wv.x + bv.x) * mk;
    y[1] = ((v.y - mean) * rs * wv.y + bv.y) * mk;
    y[2] = ((v.z - mean) * rs * wv.z + bv.z) * mk;
    y[3] = ((v.w - mean) * rs * wv.w + bv.w) * mk;
    uint2 pk;
    pk.x = (u32)f2b(y[0]) | ((u32)f2b(y[1]) << 16);
    pk.y = (u32)f2b(y[2]) | ((u32)f2b(y[3]) << 16);
    *reinterpret_cast<uint2*>(mn + (size_t)row * C_ + lane * 4) = pk;
  }
}

// ---------------- K0b: pack QKVG weights to bf16 ----------------
__global__ void k_wpack(const float* __restrict__ wq, const float* __restrict__ wk,
                        const float* __restrict__ wv, const float* __restrict__ wg,
                        u16* __restrict__ wall) {
  int j = blockIdx.x * 256 + threadIdx.x;  // 65536 threads, 4 elems each
  int mat = j >> 14;
  int o = (j & 16383) * 4;
  const float* src = (mat == 0) ? wq : (mat == 1) ? wk : (mat == 2) ? wv : wg;
  float4 v = *reinterpret_cast<const float4*>(src + o);
  uint2 pk;
  pk.x = (u32)f2b(v.x) | ((u32)f2b(v.y) << 16);
  pk.y = (u32)f2b(v.z) | ((u32)f2b(v.w) << 16);
  *reinterpret_cast<uint2*>(wall + (size_t)mat * 65536 + o) = pk;
}

// ---------------- K1: QKVG projection GEMM (A staged once, 16 B-chunks) ----------------
// q pre-scaled; v written transposed [i][h][d][s]; gate sigmoid'd + masked.
__global__ __launch_bounds__(256) void k_qkvg(
    const u16* __restrict__ mn, const float* __restrict__ mask,
    const u16* __restrict__ wall, const float* __restrict__ bg,
    u16* __restrict__ qws, u16* __restrict__ kws, u16* __restrict__ vws,
    u16* __restrict__ gws) {
  __shared__ u16 lA[64 * 256];
  __shared__ u16 lB[64 * 256];
  int tile = blockIdx.x;  // 0..1023
  int i_col = tile >> 2, s0 = (tile & 3) * 64;
  int t = threadIdx.x;
  int rowg = t >> 5, cg = t & 31;
#pragma unroll
  for (int p = 0; p < 8; ++p) {
    int row = p * 8 + rowg;
    int rg = (s0 + row) * I_ + i_col;
    *reinterpret_cast<uint4*>(&lA[row * 256 + ((cg * 8) ^ ((row & 7) << 3))]) =
        *reinterpret_cast<const uint4*>(mn + (size_t)rg * C_ + cg * 8);
  }
  int lane = t & 63, w = t >> 6;
  int wr = (w >> 1) * 32, wc = (w & 1) * 32;
  int lr = lane & 15, lk = lane >> 4;
  f32x4 zz = {0.f, 0.f, 0.f, 0.f};
  for (int chunk = 0; chunk < 16; ++chunk) {
    int mat = chunk >> 2, cb = (chunk & 3) * 64;
    __syncthreads();  // previous chunk done reading lB
#pragma unroll
    for (int p = 0; p < 8; ++p) {
      int row = p * 8 + rowg;
      *reinterpret_cast<uint4*>(&lB[row * 256 + ((cg * 8) ^ ((row & 7) << 3))]) =
          *reinterpret_cast<const uint4*>(wall + ((size_t)mat << 16) +
                                          (size_t)(cb + row) * C_ + cg * 8);
    }
    __syncthreads();
    f32x4 acc[2][2] = {{zz, zz}, {zz, zz}};
#pragma unroll
    for (int kk = 0; kk < 8; ++kk) {
      int kb = kk * 32 + lk * 8;
      int ra0 = wr + lr, ra1 = wr + 16 + lr, rb0 = wc + lr, rb1 = wc + 16 + lr;
      short8 a0 = *reinterpret_cast<const short8*>(&lA[ra0 * 256 + (kb ^ ((ra0 & 7) << 3))]);
      short8 a1 = *reinterpret_cast<const short8*>(&lA[ra1 * 256 + (kb ^ ((ra1 & 7) << 3))]);
      short8 b0 = *reinterpret_cast<const short8*>(&lB[rb0 * 256 + (kb ^ ((rb0 & 7) << 3))]);
      short8 b1 = *reinterpret_cast<const short8*>(&lB[rb1 * 256 + (kb ^ ((rb1 & 7) << 3))]);
      acc[0][0] = mfma16(a0, b0, acc[0][0]);
      acc[0][1] = mfma16(a0, b1, acc[0][1]);
      acc[1][0] = mfma16(a1, b0, acc[1][0]);
      acc[1][1] = mfma16(a1, b1, acc[1][1]);
    }
    u16* dstp = (mat == 0) ? qws : (mat == 1) ? kws : (mat == 2) ? vws : gws;
#pragma unroll
    for (int mm = 0; mm < 2; ++mm) {
#pragma unroll
      for (int nn = 0; nn < 2; ++nn) {
        int colL = wc + nn * 16 + lr;
        int hd = cb + colL;
        int h = hd >> 5, d = hd & 31;
        float bgv = (mat == 3) ? bg[hd] : 0.f;
#pragma unroll
        for (int r = 0; r < 4; ++r) {
          int rowL = wr + mm * 16 + lk * 4 + r;
          int s = s0 + rowL;
          float v = acc[mm][nn][r];
          size_t dst;
          if (mat == 2)
            dst = (((size_t)i_col * H_ + h) * D_ + d) * S_ + s;  // V transposed
          else
            dst = (((size_t)i_col * H_ + h) * S_ + s) * D_ + d;
          if (mat == 0) v *= QSCALE;
          if (mat == 3) {
            float mkv = mask[s * I_ + i_col];
            v = mkv * (1.f / (1.f + __expf(-(v + bgv))));
          }
          dstp[dst] = f2b(v);
        }
      }
    }
  }
}

// ---------------- K2: MFMA flash attention per (i,h) ----------------
__global__ __launch_bounds__(1024) void k_attn(
    u16* __restrict__ qws, const u16* __restrict__ kws,
    const u16* __restrict__ vws, const u16* __restrict__ gws,
    const float* __restrict__ mask) {
  __shared__ u16 lK[256 * 40];   // +16B row pad
  __shared__ u16 lV[32 * 264];   // V^T rows, +16B pad
  __shared__ float lMk[256];
  int bid = blockIdx.x;
  int i = bid >> 3, h = bid & 7;
  int t = threadIdx.x;
  size_t base = ((size_t)i * H_ + h) * (size_t)(S_ * D_);
  {
    int s = t >> 2, part = t & 3;
    *reinterpret_cast<uint4*>(&lK[s * 40 + part * 8]) =
        *reinterpret_cast<const uint4*>(kws + base + s * 32 + part * 8);
    int d = t >> 5, p2 = t & 31;
    *reinterpret_cast<uint4*>(&lV[d * 264 + p2 * 8]) =
        *reinterpret_cast<const uint4*>(vws + base + d * 256 + p2 * 8);
    if (t < 256) lMk[t] = mask[t * I_ + i];
  }
  __syncthreads();
  int lane = t & 63;
  int wvid = t >> 6;
  int lq = lane & 15, g = lane >> 4;
  int qbase = wvid * 16;
  short8 qf = *reinterpret_cast<const short8*>(qws + base + (size_t)(qbase + lq) * D_ + g * 8);
  f32x4 zz = {0.f, 0.f, 0.f, 0.f};
  f32x4 o0 = zz, o1 = zz;
  float mcur = -1e30f, sumd = 0.f;
  int addrP0 = (lq + ((g & 1) * 2 + 0) * 16) * 4;
  int addrP1 = (lq + ((g & 1) * 2 + 1) * 16) * 4;
  int aC0 = (g * 4 + 0) * 4, aC1 = (g * 4 + 1) * 4;
  int aC2 = (g * 4 + 2) * 4, aC3 = (g * 4 + 3) * 4;
#pragma unroll
  for (int ks = 0; ks < 8; ++ks) {
    int k0 = ks * 32;
    short8 kf0 = *reinterpret_cast<const short8*>(&lK[(k0 + lq) * 40 + g * 8]);
    short8 kf1 = *reinterpret_cast<const short8*>(&lK[(k0 + 16 + lq) * 40 + g * 8]);
    f32x4 s0 = mfma16(kf0, qf, zz);
    f32x4 s1 = mfma16(kf1, qf, zz);
    float4 mk0 = *reinterpret_cast<const float4*>(&lMk[k0 + g * 4]);
    float4 mk1 = *reinterpret_cast<const float4*>(&lMk[k0 + 16 + g * 4]);
    float sv[8];
    sv[0] = mk0.x > 0.f ? s0[0] : -1e9f;
    sv[1] = mk0.y > 0.f ? s0[1] : -1e9f;
    sv[2] = mk0.z > 0.f ? s0[2] : -1e9f;
    sv[3] = mk0.w > 0.f ? s0[3] : -1e9f;
    sv[4] = mk1.x > 0.f ? s1[0] : -1e9f;
    sv[5] = mk1.y > 0.f ? s1[1] : -1e9f;
    sv[6] = mk1.z > 0.f ? s1[2] : -1e9f;
    sv[7] = mk1.w > 0.f ? s1[3] : -1e9f;
    float tmax = fmaxf(fmaxf(fmaxf(sv[0], sv[1]), fmaxf(sv[2], sv[3])),
                       fmaxf(fmaxf(sv[4], sv[5]), fmaxf(sv[6], sv[7])));
    tmax = fmaxf(tmax, __shfl_xor(tmax, 16));
    tmax = fmaxf(tmax, __shfl_xor(tmax, 32));
    float mnew = fmaxf(mcur, tmax);
    float c = __expf(mcur - mnew);
    mcur = mnew;
    float p[8];
#pragma unroll
    for (int j = 0; j < 8; ++j) p[j] = __expf(sv[j] - mnew);
    sumd = sumd * c + ((p[0] + p[1]) + (p[2] + p[3])) + ((p[4] + p[5]) + (p[6] + p[7]));
    u32 pk00 = (u32)f2b(p[0]) | ((u32)f2b(p[1]) << 16);
    u32 pk01 = (u32)f2b(p[2]) | ((u32)f2b(p[3]) << 16);
    u32 pk10 = (u32)f2b(p[4]) | ((u32)f2b(p[5]) << 16);
    u32 pk11 = (u32)f2b(p[6]) | ((u32)f2b(p[7]) << 16);
    int b00 = __builtin_amdgcn_ds_bpermute(addrP0, (int)pk00);
    int b10 = __builtin_amdgcn_ds_bpermute(addrP0, (int)pk10);
    int b01 = __builtin_amdgcn_ds_bpermute(addrP0, (int)pk01);
    int b11 = __builtin_amdgcn_ds_bpermute(addrP0, (int)pk11);
    int b02 = __builtin_amdgcn_ds_bpermute(addrP1, (int)pk00);
    int b12 = __builtin_amdgcn_ds_bpermute(addrP1, (int)pk10);
    int b03 = __builtin_amdgcn_ds_bpermute(addrP1, (int)pk01);
    int b13 = __builtin_amdgcn_ds_bpermute(addrP1, (int)pk11);
    union { int u[4]; short8 s8; } pu;
    bool lo = (g < 2);
    pu.u[0] = lo ? b00 : b10;
    pu.u[1] = lo ? b01 : b11;
    pu.u[2] = lo ? b02 : b12;
    pu.u[3] = lo ? b03 : b13;
    float co0 = __int_as_float(__builtin_amdgcn_ds_bpermute(aC0, __float_as_int(c)));
    float co1 = __int_as_float(__builtin_amdgcn_ds_bpermute(aC1, __float_as_int(c)));
    float co2 = __int_as_float(__builtin_amdgcn_ds_bpermute(aC2, __float_as_int(c)));
    float co3 = __int_as_float(__builtin_amdgcn_ds_bpermute(aC3, __float_as_int(c)));
    o0[0] *= co0; o0[1] *= co1; o0[2] *= co2; o0[3] *= co3;
    o1[0] *= co0; o1[1] *= co1; o1[2] *= co2; o1[3] *= co3;
    short8 vf0 = *reinterpret_cast<const short8*>(&lV[lq * 264 + k0 + g * 8]);
    short8 vf1 = *reinterpret_cast<const short8*>(&lV[(16 + lq) * 264 + k0 + g * 8]);
    o0 = mfma16(pu.s8, vf0, o0);
    o1 = mfma16(pu.s8, vf1, o1);
  }
  float s2 = sumd + __shfl_xor(sumd, 16);
  float tot = s2 + __shfl_xor(s2, 32);
  float iv = 1.f / tot;
  float ivo[4];
  ivo[0] = __int_as_float(__builtin_amdgcn_ds_bpermute(aC0, __float_as_int(iv)));
  ivo[1] = __int_as_float(__builtin_amdgcn_ds_bpermute(aC1, __float_as_int(iv)));
  ivo[2] = __int_as_float(__builtin_amdgcn_ds_bpermute(aC2, __float_as_int(iv)));
  ivo[3] = __int_as_float(__builtin_amdgcn_ds_bpermute(aC3, __float_as_int(iv)));
#pragma unroll
  for (int r = 0; r < 4; ++r) {
    int row = qbase + g * 4 + r;
    size_t idx0 = base + (size_t)row * D_ + lq;
    size_t idx1 = idx0 + 16;
    float g0 = b2f((u32)gws[idx0]);
    float g1 = b2f((u32)gws[idx1]);
    qws[idx0] = f2b(o0[r] * ivo[r] * g0);
    qws[idx1] = f2b(o1[r] * ivo[r] * g1);
  }
}

// ---------------- K3: output projection (A staged once, 4 B-chunks) ----------------
__global__ __launch_bounds__(256) void k_oproj(const u16* __restrict__ ows,
                                               const float* __restrict__ wo,
                                               const float* __restrict__ bo,
                                               float* __restrict__ out) {
  __shared__ u16 lA[64 * 256];
  __shared__ u16 lB[64 * 256];
  int tile = blockIdx.x;  // 0..1023
  int r0 = tile * 64;
  int t = threadIdx.x;
  int rowg = t >> 5, cg = t & 31;
  int hh = cg >> 2, d0 = (cg & 3) * 8;
#pragma unroll
  for (int p = 0; p < 8; ++p) {
    int row = p * 8 + rowg;
    int rg = r0 + row;
    int ii = rg >> 8, ss = rg & 255;
    *reinterpret_cast<uint4*>(&lA[row * 256 + ((cg * 8) ^ ((row & 7) << 3))]) =
        *reinterpret_cast<const uint4*>(ows + (((size_t)ii * H_ + hh) * S_ + ss) * D_ + d0);
  }
  int lane = t & 63, w = t >> 6;
  int wr = (w >> 1) * 32, wc = (w & 1) * 32;
  int lr = lane & 15, lk = lane >> 4;
  f32x4 zz = {0.f, 0.f, 0.f, 0.f};
  for (int chunk = 0; chunk < 4; ++chunk) {
    int cb = chunk * 64;
    __syncthreads();
#pragma unroll
    for (int p = 0; p < 8; ++p) {
      int row = p * 8 + rowg;
      float wf[8];
      load8f(wo + (size_t)(cb + row) * HD_ + cg * 8, wf);
      *reinterpret_cast<uint4*>(&lB[row * 256 + ((cg * 8) ^ ((row & 7) << 3))]) = pack8(wf);
    }
    __syncthreads();
    f32x4 acc[2][2] = {{zz, zz}, {zz, zz}};
#pragma unroll
    for (int kk = 0; kk < 8; ++kk) {
      int kb = kk * 32 + lk * 8;
      int ra0 = wr + lr, ra1 = wr + 16 + lr, rb0 = wc + lr, rb1 = wc + 16 + lr;
      short8 a0 = *reinterpret_cast<const short8*>(&lA[ra0 * 256 + (kb ^ ((ra0 & 7) << 3))]);
      short8 a1 = *reinterpret_cast<const short8*>(&lA[ra1 * 256 + (kb ^ ((ra1 & 7) << 3))]);
      short8 b0 = *reinterpret_cast<const short8*>(&lB[rb0 * 256 + (kb ^ ((rb0 & 7) << 3))]);
      short8 b1 = *reinterpret_cast<const short8*>(&lB[rb1 * 256 + (kb ^ ((rb1 & 7) << 3))]);
      acc[0][0] = mfma16(a0, b0, acc[0][0]);
      acc[0][1] = mfma16(a0, b1, acc[0][1]);
      acc[1][0] = mfma16(a1, b0, acc[1][0]);
      acc[1][1] = mfma16(a1, b1, acc[1][1]);
    }
#pragma unroll
    for (int mm = 0; mm < 2; ++mm) {
#pragma unroll
      for (int nn = 0; nn < 2; ++nn) {
        int colL = wc + nn * 16 + lr;
        int ch = cb + colL;
        float bov = bo[ch];
#pragma unroll
        for (int r = 0; r < 4; ++r) {
          int rowL = wr + mm * 16 + lk * 4 + r;
          int rg = r0 + rowL;
          int ii = rg >> 8;
          int ss = rg & 255;
          out[((size_t)ss * I_ + ii) * C_ + ch] = acc[mm][nn][r] + bov;
        }
      }
    }
  }
}

extern "C" void kernel_launch(void* const* d_in, const int* in_sizes, int n_in,
                              void* d_out, int out_size, void* d_ws, size_t ws_size,
                              hipStream_t stream) {
  const float *m, *mask, *lnw, *lnb, *wq, *wk, *wv, *wg, *bg, *wo, *bo;
  if (in_sizes[0] > 1000000) {  // dict order
    m = (const float*)d_in[0]; mask = (const float*)d_in[1];
    lnw = (const float*)d_in[2]; lnb = (const float*)d_in[3];
    wq = (const float*)d_in[4]; wk = (const float*)d_in[5];
    wv = (const float*)d_in[6]; wg = (const float*)d_in[7];
    bg = (const float*)d_in[8]; wo = (const float*)d_in[9];
    bo = (const float*)d_in[10];
  } else {  // alphabetical fallback
    bg = (const float*)d_in[0]; bo = (const float*)d_in[1];
    lnb = (const float*)d_in[2]; lnw = (const float*)d_in[3];
    m = (const float*)d_in[4]; mask = (const float*)d_in[5];
    wg = (const float*)d_in[6]; wk = (const float*)d_in[7];
    wo = (const float*)d_in[8]; wq = (const float*)d_in[9];
    wv = (const float*)d_in[10];
  }
  float* out = (float*)d_out;

  const size_t SZ = (size_t)S_ * I_ * C_;  // 16,777,216
  u16* qws = (u16*)d_ws;   // q (pre-scaled), later overwritten with gated O
  u16* kws = qws + SZ;
  u16* vws = kws + SZ;     // V^T: [i][h][d][s]
  u16* gws = vws + SZ;
  u16* mn = gws + SZ;      // LN'd masked m in bf16, [rg][c]
  u16* wall = mn + SZ;     // packed wq,wk,wv,wg bf16

  k_lnnorm<<<2048, 256, 0, stream>>>(m, mask, lnw, lnb, mn);
  k_wpack<<<256, 256, 0, stream>>>(wq, wk, wv, wg, wall);
  k_qkvg<<<1024, 256, 0, stream>>>(mn, mask, wall, bg, qws, kws, vws, gws);
  k_attn<<<2048, 1024, 0, stream>>>(qws, kws, vws, gws, mask);
  k_oproj<<<1024, 256, 0, stream>>>(qws, wo, bo, out);
}

// Round 8
// 193.203 us; speedup vs baseline: 4.7777x; 1.2782x over previous
//
#include <hip/hip_runtime.h>

typedef unsigned short u16;
typedef unsigned int u32;
typedef __attribute__((ext_vector_type(8))) short short8;
typedef __attribute__((ext_vector_type(4))) float f32x4;

constexpr int S_ = 256, I_ = 256, C_ = 256, H_ = 8, D_ = 32, HD_ = 256;
constexpr float QSCALE = 0.17677669529663687f;  // 1/sqrt(32)

__device__ __forceinline__ float b2f(u32 u) {
  union { u32 i; float f; } x; x.i = u << 16; return x.f;
}
__device__ __forceinline__ u16 f2b(float f) {
  union { float f; u32 i; } x; x.f = f;
  u32 r = x.i + 0x7fffu + ((x.i >> 16) & 1u);
  return (u16)(r >> 16);
}
__device__ __forceinline__ uint4 pack8(const float* f) {
  uint4 r;
  r.x = (u32)f2b(f[0]) | ((u32)f2b(f[1]) << 16);
  r.y = (u32)f2b(f[2]) | ((u32)f2b(f[3]) << 16);
  r.z = (u32)f2b(f[4]) | ((u32)f2b(f[5]) << 16);
  r.w = (u32)f2b(f[6]) | ((u32)f2b(f[7]) << 16);
  return r;
}
__device__ __forceinline__ void load8f(const float* p, float* f) {
  float4 a = *reinterpret_cast<const float4*>(p);
  float4 b = *reinterpret_cast<const float4*>(p + 4);
  f[0] = a.x; f[1] = a.y; f[2] = a.z; f[3] = a.w;
  f[4] = b.x; f[5] = b.y; f[6] = b.z; f[7] = b.w;
}
__device__ __forceinline__ f32x4 mfma16(short8 a, short8 b, f32x4 c) {
  return __builtin_amdgcn_mfma_f32_16x16x32_bf16(a, b, c, 0, 0, 0);
}

// ---------------- K0: LayerNorm + mask -> bf16 m_norm ----------------
__global__ void k_lnnorm(const float* __restrict__ m, const float* __restrict__ mask,
                         const float* __restrict__ lnw, const float* __restrict__ lnb,
                         u16* __restrict__ mn) {
  int wg = (blockIdx.x * 256 + threadIdx.x) >> 6;  // 8192 waves
  int lane = threadIdx.x & 63;
  float4 wv = *reinterpret_cast<const float4*>(lnw + lane * 4);
  float4 bv = *reinterpret_cast<const float4*>(lnb + lane * 4);
  for (int it = 0; it < 8; ++it) {
    int row = wg * 8 + it;
    float4 v = *reinterpret_cast<const float4*>(m + (size_t)row * C_ + lane * 4);
    float s = v.x + v.y + v.z + v.w;
    float ss = v.x * v.x + v.y * v.y + v.z * v.z + v.w * v.w;
#pragma unroll
    for (int o = 32; o; o >>= 1) { s += __shfl_xor(s, o); ss += __shfl_xor(ss, o); }
    float mean = s * (1.f / C_);
    float var = ss * (1.f / C_) - mean * mean;
    float rs = rsqrtf(fmaxf(var, 0.f) + 1e-5f);
    float mk = mask[row];
    float y[4];
    y[0] = ((v.x - mean) * rs * wv.x + bv.x) * mk;
    y[1] = ((v.y - mean) * rs * wv.y + bv.y) * mk;
    y[2] = ((v.z - mean) * rs * wv.z + bv.z) * mk;
    y[3] = ((v.w - mean) * rs * wv.w + bv.w) * mk;
    uint2 pk;
    pk.x = (u32)f2b(y[0]) | ((u32)f2b(y[1]) << 16);
    pk.y = (u32)f2b(y[2]) | ((u32)f2b(y[3]) << 16);
    *reinterpret_cast<uint2*>(mn + (size_t)row * C_ + lane * 4) = pk;
  }
}

// ---------------- K0b: pack weights into MFMA fragment order ----------------
// group gid < 512:   qkvg  gid = ((mat*4+cbi)*2+ch2)*16 + kk*2 + nn
// group gid >= 512:  wo    g2  = (cbi*2+ch2)*16 + kk*2 + nn
// element: wall2[gid*512 + lane*8 + e] =
//          W[cbi*64 + ch2*32 + nn*16 + (lane&15)][kk*32 + (lane>>4)*8 + e]
__global__ void k_wpack(const float* __restrict__ wq, const float* __restrict__ wk,
                        const float* __restrict__ wv, const float* __restrict__ wg,
                        const float* __restrict__ wo, u16* __restrict__ wall2) {
  int gid = blockIdx.x * 4 + (threadIdx.x >> 6);
  int lane = threadIdx.x & 63;
  if (gid >= 640) return;
  const float* W;
  int g2;
  if (gid < 512) {
    int mat = gid >> 7;
    W = (mat == 0) ? wq : (mat == 1) ? wk : (mat == 2) ? wv : wg;
    g2 = gid & 127;
  } else {
    W = wo;
    g2 = gid - 512;
  }
  int nn = g2 & 1, kk = (g2 >> 1) & 7, ch2 = (g2 >> 4) & 1, cbi = (g2 >> 5) & 3;
  int row = cbi * 64 + ch2 * 32 + nn * 16 + (lane & 15);
  int k0 = kk * 32 + (lane >> 4) * 8;
  float f[8];
  load8f(W + (size_t)row * 256 + k0, f);
  *reinterpret_cast<uint4*>(wall2 + (size_t)gid * 512 + lane * 8) = pack8(f);
}

// ---------------- K1: QKVG projection (A staged once, barrier-free chunk loop) ----
__global__ __launch_bounds__(256, 4) void k_qkvg(
    const u16* __restrict__ mn, const float* __restrict__ mask,
    const u16* __restrict__ wall2, const float* __restrict__ bg,
    u16* __restrict__ qws, u16* __restrict__ kws, u16* __restrict__ vws,
    u16* __restrict__ gws) {
  __shared__ u16 lA[64 * 256];
  int tile = blockIdx.x;  // 0..1023
  int i_col = tile >> 2, s0 = (tile & 3) * 64;
  int t = threadIdx.x;
  int rowg = t >> 5, cg = t & 31;
#pragma unroll
  for (int p = 0; p < 8; ++p) {
    int row = p * 8 + rowg;
    int rg = (s0 + row) * I_ + i_col;
    *reinterpret_cast<uint4*>(&lA[row * 256 + ((cg * 8) ^ ((row & 7) << 3))]) =
        *reinterpret_cast<const uint4*>(mn + (size_t)rg * C_ + cg * 8);
  }
  __syncthreads();
  int lane = t & 63, w = t >> 6;
  int wr = (w >> 1) * 32, ch2 = w & 1, wc = ch2 * 32;
  int lr = lane & 15, lk = lane >> 4;
  f32x4 zz = {0.f, 0.f, 0.f, 0.f};
  for (int chunk = 0; chunk < 16; ++chunk) {
    int mat = chunk >> 2, cb = (chunk & 3) * 64;
    const u16* Bp = wall2 + (size_t)((chunk * 2 + ch2) * 16) * 512 + lane * 8;
    f32x4 acc[2][2] = {{zz, zz}, {zz, zz}};
#pragma unroll
    for (int kk = 0; kk < 8; ++kk) {
      int kb = kk * 32 + lk * 8;
      int ra0 = wr + lr, ra1 = wr + 16 + lr;
      short8 a0 = *reinterpret_cast<const short8*>(&lA[ra0 * 256 + (kb ^ ((ra0 & 7) << 3))]);
      short8 a1 = *reinterpret_cast<const short8*>(&lA[ra1 * 256 + (kb ^ ((ra1 & 7) << 3))]);
      short8 b0 = *reinterpret_cast<const short8*>(Bp + (kk * 2 + 0) * 512);
      short8 b1 = *reinterpret_cast<const short8*>(Bp + (kk * 2 + 1) * 512);
      acc[0][0] = mfma16(a0, b0, acc[0][0]);
      acc[0][1] = mfma16(a0, b1, acc[0][1]);
      acc[1][0] = mfma16(a1, b0, acc[1][0]);
      acc[1][1] = mfma16(a1, b1, acc[1][1]);
    }
#pragma unroll
    for (int mm = 0; mm < 2; ++mm) {
#pragma unroll
      for (int nn = 0; nn < 2; ++nn) {
        int colL = wc + nn * 16 + lr;
        int hd = cb + colL;
        int h = hd >> 5, d = hd & 31;
        if (mat == 2) {
          // V^T [i][h][d][s]: 4 consecutive s -> one uint2 store
          int sbase = s0 + wr + mm * 16 + lk * 4;
          uint2 pk;
          pk.x = (u32)f2b(acc[mm][nn][0]) | ((u32)f2b(acc[mm][nn][1]) << 16);
          pk.y = (u32)f2b(acc[mm][nn][2]) | ((u32)f2b(acc[mm][nn][3]) << 16);
          *reinterpret_cast<uint2*>(
              vws + (((size_t)i_col * H_ + h) * D_ + d) * S_ + sbase) = pk;
        } else {
          u16* dstp = (mat == 0) ? qws : (mat == 1) ? kws : gws;
          float bgv = (mat == 3) ? bg[hd] : 0.f;
#pragma unroll
          for (int r = 0; r < 4; ++r) {
            int rowL = wr + mm * 16 + lk * 4 + r;
            int s = s0 + rowL;
            float v = acc[mm][nn][r];
            if (mat == 0) v *= QSCALE;
            if (mat == 3) {
              float mkv = mask[s * I_ + i_col];
              v = mkv * (1.f / (1.f + __expf(-(v + bgv))));
            }
            dstp[(((size_t)i_col * H_ + h) * S_ + s) * D_ + d] = f2b(v);
          }
        }
      }
    }
  }
}

// ---------------- K2: MFMA flash attention per (i,h) ----------------
__global__ __launch_bounds__(1024) void k_attn(
    u16* __restrict__ qws, const u16* __restrict__ kws,
    const u16* __restrict__ vws, const u16* __restrict__ gws,
    const float* __restrict__ mask) {
  __shared__ u16 lK[256 * 40];   // +16B row pad
  __shared__ u16 lV[32 * 264];   // V^T rows, +16B pad
  __shared__ float lMk[256];
  int bid = blockIdx.x;
  int i = bid >> 3, h = bid & 7;
  int t = threadIdx.x;
  size_t base = ((size_t)i * H_ + h) * (size_t)(S_ * D_);
  {
    int s = t >> 2, part = t & 3;
    *reinterpret_cast<uint4*>(&lK[s * 40 + part * 8]) =
        *reinterpret_cast<const uint4*>(kws + base + s * 32 + part * 8);
    int d = t >> 5, p2 = t & 31;
    *reinterpret_cast<uint4*>(&lV[d * 264 + p2 * 8]) =
        *reinterpret_cast<const uint4*>(vws + base + d * 256 + p2 * 8);
    if (t < 256) lMk[t] = mask[t * I_ + i];
  }
  __syncthreads();
  int lane = t & 63;
  int wvid = t >> 6;
  int lq = lane & 15, g = lane >> 4;
  int qbase = wvid * 16;
  short8 qf = *reinterpret_cast<const short8*>(qws + base + (size_t)(qbase + lq) * D_ + g * 8);
  f32x4 zz = {0.f, 0.f, 0.f, 0.f};
  f32x4 o0 = zz, o1 = zz;
  float mcur = -1e30f, sumd = 0.f;
  int addrP0 = (lq + ((g & 1) * 2 + 0) * 16) * 4;
  int addrP1 = (lq + ((g & 1) * 2 + 1) * 16) * 4;
  int aC0 = (g * 4 + 0) * 4, aC1 = (g * 4 + 1) * 4;
  int aC2 = (g * 4 + 2) * 4, aC3 = (g * 4 + 3) * 4;
#pragma unroll
  for (int ks = 0; ks < 8; ++ks) {
    int k0 = ks * 32;
    short8 kf0 = *reinterpret_cast<const short8*>(&lK[(k0 + lq) * 40 + g * 8]);
    short8 kf1 = *reinterpret_cast<const short8*>(&lK[(k0 + 16 + lq) * 40 + g * 8]);
    f32x4 s0 = mfma16(kf0, qf, zz);
    f32x4 s1 = mfma16(kf1, qf, zz);
    float4 mk0 = *reinterpret_cast<const float4*>(&lMk[k0 + g * 4]);
    float4 mk1 = *reinterpret_cast<const float4*>(&lMk[k0 + 16 + g * 4]);
    float sv[8];
    sv[0] = mk0.x > 0.f ? s0[0] : -1e9f;
    sv[1] = mk0.y > 0.f ? s0[1] : -1e9f;
    sv[2] = mk0.z > 0.f ? s0[2] : -1e9f;
    sv[3] = mk0.w > 0.f ? s0[3] : -1e9f;
    sv[4] = mk1.x > 0.f ? s1[0] : -1e9f;
    sv[5] = mk1.y > 0.f ? s1[1] : -1e9f;
    sv[6] = mk1.z > 0.f ? s1[2] : -1e9f;
    sv[7] = mk1.w > 0.f ? s1[3] : -1e9f;
    float tmax = fmaxf(fmaxf(fmaxf(sv[0], sv[1]), fmaxf(sv[2], sv[3])),
                       fmaxf(fmaxf(sv[4], sv[5]), fmaxf(sv[6], sv[7])));
    tmax = fmaxf(tmax, __shfl_xor(tmax, 16));
    tmax = fmaxf(tmax, __shfl_xor(tmax, 32));
    float mnew = fmaxf(mcur, tmax);
    float c = __expf(mcur - mnew);
    mcur = mnew;
    float p[8];
#pragma unroll
    for (int j = 0; j < 8; ++j) p[j] = __expf(sv[j] - mnew);
    sumd = sumd * c + ((p[0] + p[1]) + (p[2] + p[3])) + ((p[4] + p[5]) + (p[6] + p[7]));
    u32 pk00 = (u32)f2b(p[0]) | ((u32)f2b(p[1]) << 16);
    u32 pk01 = (u32)f2b(p[2]) | ((u32)f2b(p[3]) << 16);
    u32 pk10 = (u32)f2b(p[4]) | ((u32)f2b(p[5]) << 16);
    u32 pk11 = (u32)f2b(p[6]) | ((u32)f2b(p[7]) << 16);
    int b00 = __builtin_amdgcn_ds_bpermute(addrP0, (int)pk00);
    int b10 = __builtin_amdgcn_ds_bpermute(addrP0, (int)pk10);
    int b01 = __builtin_amdgcn_ds_bpermute(addrP0, (int)pk01);
    int b11 = __builtin_amdgcn_ds_bpermute(addrP0, (int)pk11);
    int b02 = __builtin_amdgcn_ds_bpermute(addrP1, (int)pk00);
    int b12 = __builtin_amdgcn_ds_bpermute(addrP1, (int)pk10);
    int b03 = __builtin_amdgcn_ds_bpermute(addrP1, (int)pk01);
    int b13 = __builtin_amdgcn_ds_bpermute(addrP1, (int)pk11);
    union { int u[4]; short8 s8; } pu;
    bool lo = (g < 2);
    pu.u[0] = lo ? b00 : b10;
    pu.u[1] = lo ? b01 : b11;
    pu.u[2] = lo ? b02 : b12;
    pu.u[3] = lo ? b03 : b13;
    float co0 = __int_as_float(__builtin_amdgcn_ds_bpermute(aC0, __float_as_int(c)));
    float co1 = __int_as_float(__builtin_amdgcn_ds_bpermute(aC1, __float_as_int(c)));
    float co2 = __int_as_float(__builtin_amdgcn_ds_bpermute(aC2, __float_as_int(c)));
    float co3 = __int_as_float(__builtin_amdgcn_ds_bpermute(aC3, __float_as_int(c)));
    o0[0] *= co0; o0[1] *= co1; o0[2] *= co2; o0[3] *= co3;
    o1[0] *= co0; o1[1] *= co1; o1[2] *= co2; o1[3] *= co3;
    short8 vf0 = *reinterpret_cast<const short8*>(&lV[lq * 264 + k0 + g * 8]);
    short8 vf1 = *reinterpret_cast<const short8*>(&lV[(16 + lq) * 264 + k0 + g * 8]);
    o0 = mfma16(pu.s8, vf0, o0);
    o1 = mfma16(pu.s8, vf1, o1);
  }
  float s2 = sumd + __shfl_xor(sumd, 16);
  float tot = s2 + __shfl_xor(s2, 32);
  float iv = 1.f / tot;
  float ivo[4];
  ivo[0] = __int_as_float(__builtin_amdgcn_ds_bpermute(aC0, __float_as_int(iv)));
  ivo[1] = __int_as_float(__builtin_amdgcn_ds_bpermute(aC1, __float_as_int(iv)));
  ivo[2] = __int_as_float(__builtin_amdgcn_ds_bpermute(aC2, __float_as_int(iv)));
  ivo[3] = __int_as_float(__builtin_amdgcn_ds_bpermute(aC3, __float_as_int(iv)));
#pragma unroll
  for (int r = 0; r < 4; ++r) {
    int row = qbase + g * 4 + r;
    size_t idx0 = base + (size_t)row * D_ + lq;
    size_t idx1 = idx0 + 16;
    float g0 = b2f((u32)gws[idx0]);
    float g1 = b2f((u32)gws[idx1]);
    qws[idx0] = f2b(o0[r] * ivo[r] * g0);
    qws[idx1] = f2b(o1[r] * ivo[r] * g1);
  }
}

// ---------------- K3: output projection (A staged once, barrier-free) ----------
__global__ __launch_bounds__(256, 4) void k_oproj(const u16* __restrict__ ows,
                                                  const u16* __restrict__ wall2,
                                                  const float* __restrict__ bo,
                                                  float* __restrict__ out) {
  __shared__ u16 lA[64 * 256];
  int tile = blockIdx.x;  // 0..1023
  int r0 = tile * 64;
  int t = threadIdx.x;
  int rowg = t >> 5, cg = t & 31;
  int hh = cg >> 2, d0 = (cg & 3) * 8;
#pragma unroll
  for (int p = 0; p < 8; ++p) {
    int row = p * 8 + rowg;
    int rg = r0 + row;
    int ii = rg >> 8, ss = rg & 255;
    *reinterpret_cast<uint4*>(&lA[row * 256 + ((cg * 8) ^ ((row & 7) << 3))]) =
        *reinterpret_cast<const uint4*>(ows + (((size_t)ii * H_ + hh) * S_ + ss) * D_ + d0);
  }
  __syncthreads();
  int lane = t & 63, w = t >> 6;
  int wr = (w >> 1) * 32, ch2 = w & 1, wc = ch2 * 32;
  int lr = lane & 15, lk = lane >> 4;
  f32x4 zz = {0.f, 0.f, 0.f, 0.f};
  for (int chunk = 0; chunk < 4; ++chunk) {
    int cb = chunk * 64;
    const u16* Bp = wall2 + (size_t)(512 + (chunk * 2 + ch2) * 16) * 512 + lane * 8;
    f32x4 acc[2][2] = {{zz, zz}, {zz, zz}};
#pragma unroll
    for (int kk = 0; kk < 8; ++kk) {
      int kb = kk * 32 + lk * 8;
      int ra0 = wr + lr, ra1 = wr + 16 + lr;
      short8 a0 = *reinterpret_cast<const short8*>(&lA[ra0 * 256 + (kb ^ ((ra0 & 7) << 3))]);
      short8 a1 = *reinterpret_cast<const short8*>(&lA[ra1 * 256 + (kb ^ ((ra1 & 7) << 3))]);
      short8 b0 = *reinterpret_cast<const short8*>(Bp + (kk * 2 + 0) * 512);
      short8 b1 = *reinterpret_cast<const short8*>(Bp + (kk * 2 + 1) * 512);
      acc[0][0] = mfma16(a0, b0, acc[0][0]);
      acc[0][1] = mfma16(a0, b1, acc[0][1]);
      acc[1][0] = mfma16(a1, b0, acc[1][0]);
      acc[1][1] = mfma16(a1, b1, acc[1][1]);
    }
#pragma unroll
    for (int mm = 0; mm < 2; ++mm) {
#pragma unroll
      for (int nn = 0; nn < 2; ++nn) {
        int colL = wc + nn * 16 + lr;
        int ch = cb + colL;
        float bov = bo[ch];
#pragma unroll
        for (int r = 0; r < 4; ++r) {
          int rowL = wr + mm * 16 + lk * 4 + r;
          int rg = r0 + rowL;
          int ii = rg >> 8;
          int ss = rg & 255;
          out[((size_t)ss * I_ + ii) * C_ + ch] = acc[mm][nn][r] + bov;
        }
      }
    }
  }
}

extern "C" void kernel_launch(void* const* d_in, const int* in_sizes, int n_in,
                              void* d_out, int out_size, void* d_ws, size_t ws_size,
                              hipStream_t stream) {
  const float *m, *mask, *lnw, *lnb, *wq, *wk, *wv, *wg, *bg, *wo, *bo;
  if (in_sizes[0] > 1000000) {  // dict order
    m = (const float*)d_in[0]; mask = (const float*)d_in[1];
    lnw = (const float*)d_in[2]; lnb = (const float*)d_in[3];
    wq = (const float*)d_in[4]; wk = (const float*)d_in[5];
    wv = (const float*)d_in[6]; wg = (const float*)d_in[7];
    bg = (const float*)d_in[8]; wo = (const float*)d_in[9];
    bo = (const float*)d_in[10];
  } else {  // alphabetical fallback
    bg = (const float*)d_in[0]; bo = (const float*)d_in[1];
    lnb = (const float*)d_in[2]; lnw = (const float*)d_in[3];
    m = (const float*)d_in[4]; mask = (const float*)d_in[5];
    wg = (const float*)d_in[6]; wk = (const float*)d_in[7];
    wo = (const float*)d_in[8]; wq = (const float*)d_in[9];
    wv = (const float*)d_in[10];
  }
  float* out = (float*)d_out;

  const size_t SZ = (size_t)S_ * I_ * C_;  // 16,777,216
  u16* qws = (u16*)d_ws;   // q (pre-scaled), later overwritten with gated O
  u16* kws = qws + SZ;
  u16* vws = kws + SZ;     // V^T: [i][h][d][s]
  u16* gws = vws + SZ;
  u16* mn = gws + SZ;      // LN'd masked m in bf16, [rg][c]
  u16* wall2 = mn + SZ;    // fragment-ordered weights: 640 groups x 512 u16

  k_lnnorm<<<2048, 256, 0, stream>>>(m, mask, lnw, lnb, mn);
  k_wpack<<<160, 256, 0, stream>>>(wq, wk, wv, wg, wo, wall2);
  k_qkvg<<<1024, 256, 0, stream>>>(mn, mask, wall2, bg, qws, kws, vws, gws);
  k_attn<<<2048, 1024, 0, stream>>>(qws, kws, vws, gws, mask);
  k_oproj<<<1024, 256, 0, stream>>>(qws, wall2, bo, out);
}